// Round 1
// baseline (195.110 us; speedup 1.0000x reference)
//
#include <hip/hip_runtime.h>
#include <stdint.h>

// Input  x[b,t,h,w,c] : (4, 200, 64, 64, 8) fp32, n = h*512 + w*8 + c (=h*512+wc)
// Output out[b,t,w,c,h]: (4, 200, 64, 8, 64) fp32, idx = (b*200+t)*32768 + wc*64 + h
// Per neuron, per 100-step chunk: acc += x[t]; if (acc > 2) { spike=1; acc=0; }
//
// Single fused kernel (no workspace):
//   grid 512 = slab(8 = b*2+chunk) x hHalf(2) x wcTile(32 tiles of 16)
//   block 256 threads, 2 neurons/thread.
//   Phase 1: float2 strided loads (64B-aligned segments), scan 100 steps,
//            pack spike bits into 4 u32/neuron, store to padded LDS plane.
//   Phase 2: hoist 16 bit-words to registers, 50 coalesced float4 stores
//            (per wave: 8 x 128B aligned segments, full-line writes).
#define HWC   32768
#define TTOT  200
#define CHUNK 100

__global__ __launch_bounds__(256) void spike_fused(const float* __restrict__ x,
                                                   float* __restrict__ out) {
    // [tw 0..3][hl 0..31][wcl 0..15 pad 17] -> 4*544 u32 = 8.7 KB
    __shared__ uint32_t lds[4 * 544];

    unsigned bid  = blockIdx.x;            // [0,512)
    unsigned slab = bid >> 6;              // [0,8)
    unsigned hh   = (bid >> 5) & 1u;       // h half: 0/1
    unsigned tile = bid & 31u;             // wc tile: [0,32)
    unsigned b    = slab >> 1, ch = slab & 1u;
    unsigned h0   = hh * 32u;
    unsigned wc0  = tile * 16u;
    unsigned tid  = threadIdx.x;

    // ---------------- phase 1: integrate-and-fire scan -> bits in LDS ------
    {
        unsigned hl = tid >> 3;            // [0,32)
        unsigned wq = tid & 7u;            // [0,8) -> local wc = 2*wq, 2*wq+1
        unsigned n  = (h0 + hl) * 512u + wc0 + wq * 2u;
        const float2* xp = (const float2*)x
            + (((size_t)(b * TTOT + ch * CHUNK) * HWC + n) >> 1);

        float a0 = 0.0f, a1 = 0.0f;
        uint32_t wa[4] = {0u, 0u, 0u, 0u};
        uint32_t wb[4] = {0u, 0u, 0u, 0u};

#define STEP(TW, BB, K)                                                     \
    do {                                                                    \
        a0 += v[K].x;                                                       \
        if (a0 > 2.0f) { wa[TW] |= (1u << ((BB) + (K))); a0 = 0.0f; }       \
        a1 += v[K].y;                                                       \
        if (a1 > 2.0f) { wb[TW] |= (1u << ((BB) + (K))); a1 = 0.0f; }       \
    } while (0)

#define GROUP8(TW, TBASE)                                                   \
    do {                                                                    \
        float2 v[8];                                                        \
        _Pragma("unroll")                                                   \
        for (int k = 0; k < 8; ++k)                                         \
            v[k] = xp[(size_t)((TBASE) + k) * (HWC / 2)];                   \
        STEP(TW, (TBASE) & 31, 0); STEP(TW, (TBASE) & 31, 1);               \
        STEP(TW, (TBASE) & 31, 2); STEP(TW, (TBASE) & 31, 3);               \
        STEP(TW, (TBASE) & 31, 4); STEP(TW, (TBASE) & 31, 5);               \
        STEP(TW, (TBASE) & 31, 6); STEP(TW, (TBASE) & 31, 7);               \
    } while (0)

        GROUP8(0,  0); GROUP8(0,  8); GROUP8(0, 16); GROUP8(0, 24);
        GROUP8(1, 32); GROUP8(1, 40); GROUP8(1, 48); GROUP8(1, 56);
        GROUP8(2, 64); GROUP8(2, 72); GROUP8(2, 80); GROUP8(2, 88);
        {   // t = 96..99 -> bits 0..3 of word 3
            float2 v[4];
#pragma unroll
            for (int k = 0; k < 4; ++k)
                v[k] = xp[(size_t)(96 + k) * (HWC / 2)];
            STEP(3, 0, 0); STEP(3, 0, 1); STEP(3, 0, 2); STEP(3, 0, 3);
        }
#undef GROUP8
#undef STEP

        unsigned lbase = hl * 17u + wq * 2u;
#pragma unroll
        for (int tw = 0; tw < 4; ++tw) {
            lds[tw * 544u + lbase]      = wa[tw];
            lds[tw * 544u + lbase + 1u] = wb[tw];
        }
    }
    __syncthreads();

    // ---------------- phase 2: bit expand + transpose -> coalesced stores --
    unsigned idx  = tid & 127u;
    unsigned half = tid >> 7;              // wave-uniform t parity
    unsigned wcl  = idx >> 3;              // [0,16)
    unsigned hl4  = (idx & 7u) * 4u;       // 0,4,...,28

    uint32_t r[4][4];                      // [k][tw], all indices compile-time
#pragma unroll
    for (int k = 0; k < 4; ++k)
#pragma unroll
        for (int tw = 0; tw < 4; ++tw)
            r[k][tw] = lds[tw * 544u + (hl4 + k) * 17u + wcl];

    unsigned rbase = b * TTOT + ch * CHUNK;
    size_t   cbase = (size_t)(wc0 + wcl) * 16u + ((h0 + hl4) >> 2);
    float4*  o4    = (float4*)out;

#pragma unroll
    for (int tw = 0; tw < 4; ++tw) {
        const int nj = (tw < 3) ? 16 : 2;  // last word holds t=96..99 only
        for (int j = 0; j < nj; ++j) {
            unsigned bit = 2u * (unsigned)j + half;
            unsigned t   = (unsigned)tw * 32u + bit;
            float4 v;
            v.x = (float)((r[0][tw] >> bit) & 1u);
            v.y = (float)((r[1][tw] >> bit) & 1u);
            v.z = (float)((r[2][tw] >> bit) & 1u);
            v.w = (float)((r[3][tw] >> bit) & 1u);
            o4[((size_t)(rbase + t) << 13) + cbase] = v;
        }
    }
}

extern "C" void kernel_launch(void* const* d_in, const int* in_sizes, int n_in,
                              void* d_out, int out_size, void* d_ws, size_t ws_size,
                              hipStream_t stream) {
    (void)in_sizes; (void)n_in; (void)out_size; (void)d_ws; (void)ws_size;
    const float* x = (const float*)d_in[0];
    float* out = (float*)d_out;
    hipLaunchKernelGGL(spike_fused, dim3(512), dim3(256), 0, stream, x, out);
}

// Round 2
// 194.857 us; speedup vs baseline: 1.0013x; 1.0013x over previous
//
#include <hip/hip_runtime.h>
#include <stdint.h>

// Input  x[b,t,h,w,c] : (4, 200, 64, 64, 8) fp32, n = h*512 + wc (wc = w*8+c)
// Output out[b,t,w,c,h]: (4, 200, 64, 8, 64) fp32, idx = plane*32768 + wc*64 + h
// Per neuron, per 100-step chunk: acc += x[t]; if (acc > 2) { spike=1; acc=0; }
//
// Single fused kernel, 512 blocks x 512 threads (16 waves/CU):
//   block = slab(8 = b*2+chunk) x hHalf(2 x 32h) x wcTile(32 x 16wc)
//   Phase 1: 1 neuron/thread, dword loads, DOUBLE-BUFFERED prefetch of 16
//            t-steps (16-32 dwords in flight/thread -> 64-128 KB/CU MLP),
//            spike bits packed into 4 u32, stored to padded LDS.
//   Phase 2: hoist 16 bit-words to registers, 25 coalesced float4 stores
//            per thread (128 B aligned full-line segments).
#define HWC   32768
#define TTOT  200
#define CHUNK 100

__global__ __launch_bounds__(512, 4) void spike_fused(const float* __restrict__ x,
                                                      float* __restrict__ out) {
    // [tw 0..3][hl 0..31][wcl 0..15 pad 17] -> 4*544 u32 = 8.7 KB
    __shared__ uint32_t lds[4 * 544];

    unsigned bid  = blockIdx.x;            // [0,512)
    unsigned slab = bid >> 6;              // [0,8)
    unsigned hh   = (bid >> 5) & 1u;       // h half: 0/1
    unsigned tile = bid & 31u;             // wc tile: [0,32)
    unsigned b    = slab >> 1, ch = slab & 1u;
    unsigned h0   = hh * 32u;
    unsigned wc0  = tile * 16u;
    unsigned tid  = threadIdx.x;

    // ---------------- phase 1: integrate-and-fire scan -> bits in LDS ------
    {
        unsigned hl  = tid >> 4;           // [0,32)
        unsigned wcl = tid & 15u;          // [0,16)
        unsigned n   = (h0 + hl) * 512u + wc0 + wcl;
        const float* xp = x + (size_t)(b * TTOT + ch * CHUNK) * HWC + n;

        float acc = 0.0f;
        uint32_t w[4] = {0u, 0u, 0u, 0u};
        float A[16], B[16], Tl[4];

#define LOAD16(V, TBASE)                                                    \
    do {                                                                    \
        _Pragma("unroll")                                                   \
        for (int k = 0; k < 16; ++k)                                        \
            V[k] = xp[(size_t)((TBASE) + k) * HWC];                         \
    } while (0)

#define CONS16(V, TBASE)                                                    \
    do {                                                                    \
        _Pragma("unroll")                                                   \
        for (int k = 0; k < 16; ++k) {                                      \
            acc += V[k];                                                    \
            if (acc > 2.0f) {                                               \
                w[(TBASE) >> 5] |= (1u << (((TBASE) & 31) + k));            \
                acc = 0.0f;                                                 \
            }                                                               \
        }                                                                   \
    } while (0)

        LOAD16(A, 0);
        LOAD16(B, 16);
        CONS16(A, 0);
        LOAD16(A, 32);
        CONS16(B, 16);
        LOAD16(B, 48);
        CONS16(A, 32);
        LOAD16(A, 64);
        CONS16(B, 48);
        LOAD16(B, 80);
        CONS16(A, 64);
        {   // tail prefetch t = 96..99
#pragma unroll
            for (int k = 0; k < 4; ++k)
                Tl[k] = xp[(size_t)(96 + k) * HWC];
        }
        CONS16(B, 80);
#pragma unroll
        for (int k = 0; k < 4; ++k) {      // consume tail: word 3, bits 0..3
            acc += Tl[k];
            if (acc > 2.0f) { w[3] |= (1u << k); acc = 0.0f; }
        }
#undef LOAD16
#undef CONS16

        unsigned lbase = hl * 17u + wcl;
#pragma unroll
        for (int tw = 0; tw < 4; ++tw)
            lds[tw * 544u + lbase] = w[tw];
    }
    __syncthreads();

    // ---------------- phase 2: bit expand + transpose -> coalesced stores --
    unsigned idx  = tid & 127u;            // float4-slot within t-plane
    unsigned half = tid >> 7;              // [0,4) t parity (wave-uniform)
    unsigned wcl  = idx >> 3;              // [0,16)
    unsigned h4   = (idx & 7u) * 4u;       // 0,4,...,28

    uint32_t r[4][4];                      // [k][tw], all indices compile-time
#pragma unroll
    for (int k = 0; k < 4; ++k)
#pragma unroll
        for (int tw = 0; tw < 4; ++tw)
            r[k][tw] = lds[tw * 544u + (h4 + k) * 17u + wcl];

    unsigned rbase = b * TTOT + ch * CHUNK;
    size_t   cbase = (size_t)(wc0 + wcl) * 16u + ((h0 + h4) >> 2);
    float4*  o4    = (float4*)out;

#pragma unroll
    for (int tw = 0; tw < 3; ++tw) {       // words 0..2: 8 bits each thread
        for (int j = 0; j < 8; ++j) {
            unsigned bit = 4u * (unsigned)j + half;
            unsigned t   = (unsigned)tw * 32u + bit;
            float4 v;
            v.x = (float)((r[0][tw] >> bit) & 1u);
            v.y = (float)((r[1][tw] >> bit) & 1u);
            v.z = (float)((r[2][tw] >> bit) & 1u);
            v.w = (float)((r[3][tw] >> bit) & 1u);
            o4[((size_t)(rbase + t) << 13) + cbase] = v;
        }
    }
    {   // word 3: bits 0..3 -> one store per thread (t = 96..99)
        unsigned bit = half;
        unsigned t   = 96u + bit;
        float4 v;
        v.x = (float)((r[0][3] >> bit) & 1u);
        v.y = (float)((r[1][3] >> bit) & 1u);
        v.z = (float)((r[2][3] >> bit) & 1u);
        v.w = (float)((r[3][3] >> bit) & 1u);
        o4[((size_t)(rbase + t) << 13) + cbase] = v;
    }
}

extern "C" void kernel_launch(void* const* d_in, const int* in_sizes, int n_in,
                              void* d_out, int out_size, void* d_ws, size_t ws_size,
                              hipStream_t stream) {
    (void)in_sizes; (void)n_in; (void)out_size; (void)d_ws; (void)ws_size;
    const float* x = (const float*)d_in[0];
    float* out = (float*)d_out;
    hipLaunchKernelGGL(spike_fused, dim3(512), dim3(512), 0, stream, x, out);
}

// Round 3
// 181.268 us; speedup vs baseline: 1.0764x; 1.0750x over previous
//
#include <hip/hip_runtime.h>
#include <stdint.h>

// Input  x[b,t,h,w,c] : (4, 200, 64, 64, 8) fp32, n = h*512 + wc (wc = w*8+c)
// Output out[b,t,w,c,h]: (4, 200, 64, 8, 64) fp32
// Per neuron, per 100-step chunk: acc += x[t]; if (acc > 2) { spike=1; acc=0; }
//
// Two kernels coupled by a 4 MB bit-plane workspace (L2/L3-resident):
//  K1 spike_bits4: read-optimal. 256 blocks x 256 threads, thread = 4
//     consecutive neurons (float4 loads) -> 4 KB contiguous per (block, t)
//     => full DRAM rows per activation. Deep A/B prefetch. uint4 bit stores.
//  K2 expand_bits: write-optimal (proven round-0 kernel). 8 KB contiguous
//     float4 stores per (block, t); bit reads served from L2/L3.
#define HWC    32768
#define NSLAB  8
#define TTOT   200
#define CHUNK  100

// ---------------- K1: bit-packed integrate-and-fire scan (float4) ----------
__global__ __launch_bounds__(256) void spike_bits4(const float* __restrict__ x,
                                                   uint32_t* __restrict__ spk) {
    unsigned g    = blockIdx.x * 256u + threadIdx.x;   // [0, 65536)
    unsigned slab = g >> 13;                           // [0, 8)
    unsigned n0   = (g & 8191u) * 4u;                  // 4 consecutive neurons
    unsigned b    = slab >> 1, ch = slab & 1u;
    const float4* xp = (const float4*)(x + (size_t)(b * TTOT + ch * CHUNK) * HWC + n0);

    float a0 = 0.0f, a1 = 0.0f, a2 = 0.0f, a3 = 0.0f;
    uint32_t w[4][4] = {{0u,0u,0u,0u},{0u,0u,0u,0u},{0u,0u,0u,0u},{0u,0u,0u,0u}};
    float4 A[8], B[8], Tl[4];

#define LOAD8(V, TBASE)                                                     \
    do {                                                                    \
        _Pragma("unroll")                                                   \
        for (int k = 0; k < 8; ++k)                                         \
            V[k] = xp[(size_t)((TBASE) + k) * (HWC / 4)];                   \
    } while (0)

#define CONS8(V, TBASE)                                                     \
    do {                                                                    \
        _Pragma("unroll")                                                   \
        for (int k = 0; k < 8; ++k) {                                       \
            const int tw = (TBASE) >> 5, bb = ((TBASE) & 31) + k;           \
            a0 += V[k].x; if (a0 > 2.0f) { w[tw][0] |= (1u << bb); a0 = 0.0f; } \
            a1 += V[k].y; if (a1 > 2.0f) { w[tw][1] |= (1u << bb); a1 = 0.0f; } \
            a2 += V[k].z; if (a2 > 2.0f) { w[tw][2] |= (1u << bb); a2 = 0.0f; } \
            a3 += V[k].w; if (a3 > 2.0f) { w[tw][3] |= (1u << bb); a3 = 0.0f; } \
        }                                                                   \
    } while (0)

    LOAD8(A, 0);  LOAD8(B, 8);
    CONS8(A, 0);  LOAD8(A, 16);
    CONS8(B, 8);  LOAD8(B, 24);
    CONS8(A, 16); LOAD8(A, 32);
    CONS8(B, 24); LOAD8(B, 40);
    CONS8(A, 32); LOAD8(A, 48);
    CONS8(B, 40); LOAD8(B, 56);
    CONS8(A, 48); LOAD8(A, 64);
    CONS8(B, 56); LOAD8(B, 72);
    CONS8(A, 64); LOAD8(A, 80);
    CONS8(B, 72); LOAD8(B, 88);
    CONS8(A, 80);
    {   // tail prefetch t = 96..99
#pragma unroll
        for (int k = 0; k < 4; ++k)
            Tl[k] = xp[(size_t)(96 + k) * (HWC / 4)];
    }
    CONS8(B, 88);
#pragma unroll
    for (int k = 0; k < 4; ++k) {          // consume tail: word 3, bits 0..3
        a0 += Tl[k].x; if (a0 > 2.0f) { w[3][0] |= (1u << k); a0 = 0.0f; }
        a1 += Tl[k].y; if (a1 > 2.0f) { w[3][1] |= (1u << k); a1 = 0.0f; }
        a2 += Tl[k].z; if (a2 > 2.0f) { w[3][2] |= (1u << k); a2 = 0.0f; }
        a3 += Tl[k].w; if (a3 > 2.0f) { w[3][3] |= (1u << k); a3 = 0.0f; }
    }
#undef LOAD8
#undef CONS8

    uint32_t* sp = spk + ((size_t)slab << 17);   // slab stride = 4*HWC u32
#pragma unroll
    for (int tw = 0; tw < 4; ++tw) {
        uint4 o; o.x = w[tw][0]; o.y = w[tw][1]; o.z = w[tw][2]; o.w = w[tw][3];
        *(uint4*)(sp + (size_t)tw * HWC + n0) = o;
    }
}

// ---------------- K2: bit expand + transpose (proven round-0 kernel) -------
__global__ __launch_bounds__(512) void expand_bits(const uint32_t* __restrict__ spk,
                                                   float* __restrict__ out) {
    __shared__ uint32_t lds[2 * 2112];           // 2 planes x 64h x 33 (pad)
    unsigned gid  = blockIdx.x;                  // [0, 512)
    unsigned slab = gid >> 6;
    unsigned q    = (gid >> 4) & 3u;
    unsigned tile = gid & 15u;
    unsigned wc0  = tile * 32u;
    unsigned t0   = q * 25u;
    unsigned p0   = t0 >> 5;                     // first bit-plane (0,0,1,2)
    unsigned p1   = (t0 + 24u) >> 5;             // second bit-plane (0,1,2,3)
    unsigned tid  = threadIdx.x;

    const uint32_t* sbase = spk + ((size_t)slab << 17);
#pragma unroll
    for (int it = 0; it < 8; ++it) {
        unsigned idx = it * 512u + tid;          // [0, 4096)
        unsigned pl  = idx >> 11;                // 0 / 1
        unsigned r   = idx & 2047u;
        unsigned h   = r >> 5, wcl = r & 31u;
        unsigned tw  = pl ? p1 : p0;
        lds[pl * 2112u + h * 33u + wcl] =
            sbase[((size_t)tw << 15) + h * 512u + wc0 + wcl];
    }
    __syncthreads();

    unsigned wcl = tid >> 4;                     // [0, 32)
    unsigned h0  = (tid & 15u) * 4u;             // 0,4,...,60
    uint32_t r0[4], r1[4];
#pragma unroll
    for (int k = 0; k < 4; ++k) {                // 2-way bank aliasing (free)
        r0[k] = lds[(h0 + k) * 33u + wcl];
        r1[k] = lds[2112u + (h0 + k) * 33u + wcl];
    }

    unsigned b = slab >> 1, ch = slab & 1u;
    unsigned rbase = b * TTOT + ch * CHUNK;      // output region index base
    float4* o4 = (float4*)out;

#pragma unroll
    for (int j = 0; j < 25; ++j) {
        unsigned t   = t0 + j;
        unsigned sel = (t >> 5) != p0;           // wave-uniform
        unsigned bit = t & 31u;
        uint32_t a0 = sel ? r1[0] : r0[0];
        uint32_t a1 = sel ? r1[1] : r0[1];
        uint32_t a2 = sel ? r1[2] : r0[2];
        uint32_t a3 = sel ? r1[3] : r0[3];
        float4 v;
        v.x = (float)((a0 >> bit) & 1u);
        v.y = (float)((a1 >> bit) & 1u);
        v.z = (float)((a2 >> bit) & 1u);
        v.w = (float)((a3 >> bit) & 1u);
        o4[(size_t)(rbase + t) * 8192u + wc0 * 16u + tid] = v;
    }
}

// ---------------- Fallback (ws too small): in-place scheme -----------------
__global__ __launch_bounds__(256) void spike_kernel_ip(const float* __restrict__ x,
                                                       uint8_t* __restrict__ spk) {
    unsigned g     = blockIdx.x * 256u + threadIdx.x;
    unsigned chunk = g >> 16;
    unsigned p     = g & 65535u;
    unsigned b     = p >> 14;
    unsigned i     = (p & 16383u) * 2u;
    unsigned t0    = b * TTOT + chunk * CHUNK;
    const float2* xp = (const float2*)(x + (size_t)t0 * HWC + i);
    uint8_t*      sp = spk + (size_t)t0 * 131072u + i;
    float a0 = 0.0f, a1 = 0.0f;
    for (int tb = 0; tb < CHUNK; tb += 4) {
        float2 v[4];
#pragma unroll
        for (int k = 0; k < 4; ++k) v[k] = xp[(size_t)k * (HWC / 2)];
        xp += 4 * (HWC / 2);
#pragma unroll
        for (int k = 0; k < 4; ++k) {
            a0 += v[k].x; a1 += v[k].y;
            unsigned s0 = 0u, s1 = 0u;
            if (a0 > 2.0f) { s0 = 1u; a0 = 0.0f; }
            if (a1 > 2.0f) { s1 = 1u; a1 = 0.0f; }
            *(uint16_t*)sp = (uint16_t)(s0 | (s1 << 8));
            sp += 131072u;
        }
    }
}

__global__ __launch_bounds__(512) void transpose_ip(float* __restrict__ out) {
    __shared__ uint32_t lds[64 * 129];
    unsigned region = blockIdx.x;
    unsigned tid = threadIdx.x;
    const uint32_t* in32 = (const uint32_t*)((const uint8_t*)out + (size_t)region * 131072u);
#pragma unroll
    for (int it = 0; it < 16; ++it) {
        unsigned idx = it * 512u + tid;
        unsigned h = idx >> 7, wq = idx & 127u;
        lds[h * 129u + wq] = in32[idx];
    }
    __syncthreads();
    float4* out4 = (float4*)out + (size_t)region * 8192u;
#pragma unroll
    for (int it = 0; it < 16; ++it) {
        unsigned f  = it * 512u + tid;
        unsigned wc = f >> 4;
        unsigned h0 = (f & 15u) << 2;
        unsigned wq = wc >> 2, sel = (wc & 3u) * 8u;
        float4 v;
        v.x = (float)((lds[(h0 + 0u) * 129u + wq] >> sel) & 1u);
        v.y = (float)((lds[(h0 + 1u) * 129u + wq] >> sel) & 1u);
        v.z = (float)((lds[(h0 + 2u) * 129u + wq] >> sel) & 1u);
        v.w = (float)((lds[(h0 + 3u) * 129u + wq] >> sel) & 1u);
        out4[f] = v;
    }
}

extern "C" void kernel_launch(void* const* d_in, const int* in_sizes, int n_in,
                              void* d_out, int out_size, void* d_ws, size_t ws_size,
                              hipStream_t stream) {
    (void)in_sizes; (void)n_in; (void)out_size;
    const float* x = (const float*)d_in[0];
    float* out = (float*)d_out;

    const size_t bit_bytes = (size_t)NSLAB * 4u * HWC * 4u;   // 4 MB
    if (ws_size >= bit_bytes) {
        uint32_t* spk = (uint32_t*)d_ws;
        hipLaunchKernelGGL(spike_bits4, dim3(256), dim3(256), 0, stream, x, spk);
        hipLaunchKernelGGL(expand_bits, dim3(512), dim3(512), 0, stream, spk, out);
    } else {
        hipLaunchKernelGGL(spike_kernel_ip, dim3(512), dim3(256), 0, stream, x, (uint8_t*)out);
        hipLaunchKernelGGL(transpose_ip, dim3(NSLAB * CHUNK), dim3(512), 0, stream, out);
    }
}